// Round 1
// baseline (492.106 us; speedup 1.0000x reference)
//
#include <hip/hip_runtime.h>

// ConvLSTM2D via MFMA implicit-GEMM. B=8,T=16,H=W=64,Cin=32,F=64,3x3 SAME.
// Round 8: B-fragments stream global->VGPR directly (2-deep register
// rotation) instead of the R7 LDS ring. Rationale: B-frags are wave-private
// (wave w consumes only nt in {w,w+4,w+8,w+12}), so the LDS ring provided
// prefetch only -- registers do that without the ds_write+ds_read round
// trip. This removes 8 KB of 12 KB per-wave-iteration LDS traffic (LDS was
// the largest per-CU pipe demand at ~9.7us/step vs MFMA ~7us) and the
// lgkm latency hop from the K-loop critical path. Unlike the failed R3/R6
// bulk hoists (~400+ VGPRs), the rotation adds only 32 VGPRs.
//
// Per block: 8x8 px tile x 256 z-ch, 4 waves. Wave w owns n-tiles
// {w,w+4,w+8,w+12} -> gates i/f/c/o for channel w*16+col in the same
// lane/reg (shuffle-free epilogue). A halos in LDS bf16 (pad 40/72).
// Weights prepacked [s(27)][nt(16)][lane(64)][8] -> per-(s,nt) 1KB
// contiguous, 16B/lane coalesced loads. h ping-pongs bf16 in ws; c fp32
// in d_out.

#define TSTEPS 16

typedef short bf16x8 __attribute__((ext_vector_type(8)));
typedef float f32x4 __attribute__((ext_vector_type(4)));

__device__ __forceinline__ float hsig(float x) {
    return fminf(fmaxf((x + 3.0f) * (1.0f / 6.0f), 0.0f), 1.0f);
}

__device__ __forceinline__ unsigned short f2bf(float f) {
    union { float f; unsigned int u; } v; v.f = f;
    unsigned int r = v.u + 0x7fffu + ((v.u >> 16) & 1u);  // RNE
    return (unsigned short)(r >> 16);
}

// ---- weight prepack: Wg(3,3,32,256), Ug(3,3,64,256) fp32 -> bf16 B-frags ----
__global__ __launch_bounds__(256)
void prepack_w(const float* __restrict__ Wg, const float* __restrict__ Ug,
               unsigned short* __restrict__ out)
{
    int idx = blockIdx.x * 256 + threadIdx.x;   // 27*16*64 = 27648
    if (idx >= 27648) return;
    int lane = idx & 63;
    int nt   = (idx >> 6) & 15;
    int s    = idx >> 10;
    int col = lane & 15, quad = lane >> 4;
    int n = nt * 16 + col;
    int k0 = quad * 8;
    const float* src;
    if (s < 9) {
        src = Wg + ((size_t)s * 32 + k0) * 256 + n;
    } else {
        int ss = s - 9; int tap = ss >> 1; int half = ss & 1;
        src = Ug + ((size_t)tap * 64 + half * 32 + k0) * 256 + n;
    }
    unsigned short tmp[8];
    #pragma unroll
    for (int j = 0; j < 8; ++j) tmp[j] = f2bf(src[(size_t)j * 256]);
    *(uint4*)(out + (size_t)idx * 8) = *(uint4*)tmp;
}

// ---- one ConvLSTM step (NS = 9 for t==0, 27 otherwise) ----
template<int NS>
__global__ __launch_bounds__(256)
__attribute__((amdgpu_waves_per_eu(2, 2)))
void convlstm_step(const float* __restrict__ x,       // (B,T,64,64,32) fp32
                   const unsigned short* __restrict__ wpk,
                   const float* __restrict__ bias,    // (256)
                   const unsigned short* __restrict__ h_in, // bf16 (B,64,64,64)
                   float* __restrict__ c_st,          // fp32 (B,64,64,64) = d_out
                   unsigned short* __restrict__ h_out,// bf16 ping
                   int t, int is_last)
{
    constexpr bool HP = (NS == 27);

    __shared__ __align__(16) unsigned short xs_s[100 * 40];           // 8.0 KB
    __shared__ __align__(16) unsigned short hs_s[HP ? 100 * 72 : 8];  // 14.4 KB

    const int tid = threadIdx.x;
    const int gx0 = blockIdx.x * 8;
    const int gy0 = blockIdx.y * 8;
    const int b   = blockIdx.z;

    // ---- stage x halo (fp32 -> bf16) ----
    {
        const float* xt = x + (((size_t)b * TSTEPS + t) * (size_t)(64 * 64 * 32));
        #pragma unroll 4
        for (int idx = tid; idx < 100 * 8; idx += 256) {
            int pix = idx >> 3, q = idx & 7;
            int iy = pix / 10, ix = pix - iy * 10;
            int gy = gy0 + iy - 1, gx = gx0 + ix - 1;
            unsigned short o[4] = {0, 0, 0, 0};
            if ((unsigned)gy < 64u && (unsigned)gx < 64u) {
                float4 v = *(const float4*)(xt + ((size_t)(gy * 64 + gx) * 32) + q * 4);
                o[0] = f2bf(v.x); o[1] = f2bf(v.y); o[2] = f2bf(v.z); o[3] = f2bf(v.w);
            }
            *(ushort4*)(xs_s + pix * 40 + q * 4) = *(ushort4*)o;
        }
    }
    // ---- stage h halo (bf16 copy) ----
    if constexpr (HP) {
        const unsigned short* hb = h_in + ((size_t)b * (64 * 64 * 64));
        #pragma unroll 4
        for (int idx = tid; idx < 100 * 8; idx += 256) {
            int pix = idx >> 3, q = idx & 7;
            int iy = pix / 10, ix = pix - iy * 10;
            int gy = gy0 + iy - 1, gx = gx0 + ix - 1;
            uint4 v = make_uint4(0u, 0u, 0u, 0u);
            if ((unsigned)gy < 64u && (unsigned)gx < 64u)
                v = *(const uint4*)(hb + ((size_t)(gy * 64 + gx) * 64) + q * 8);
            *(uint4*)(hs_s + pix * 72 + q * 8) = v;
        }
    }
    __syncthreads();   // staging visible

    const int lane = tid & 63;
    const int w    = tid >> 6;
    const int quad = lane >> 4;
    const int m    = lane & 15;
    const int col  = m;
    const int ch   = w * 16 + col;   // output channel 0..63

    int xb[4], hb_[4];
    #pragma unroll
    for (int mt = 0; mt < 4; ++mt) {
        int p = mt * 16 + m;
        int py = p >> 3, px = p & 7;
        xb[mt]  = (py * 10 + px) * 40 + quad * 8;
        hb_[mt] = (py * 10 + px) * 72 + quad * 8;
    }

    // ---- B streaming: direct global -> VGPR, 2-deep rotation ----
    // wpk layout: [s(27)][nt(16)][lane(64)][8 shorts] -> per (s,nt) the
    // wave's 64 lanes read one contiguous 1 KB line (16 B/lane).
    auto loadB = [&](int s, bf16x8* dst) {
        #pragma unroll
        for (int g = 0; g < 4; ++g) {
            int nt = w + 4 * g;
            dst[g] = *(const bf16x8*)(wpk + ((size_t)(s * 16 + nt) * 64 + lane) * 8);
        }
    };

    // acc init = bias
    f32x4 acc[4][4];   // [mt][gate]
    #pragma unroll
    for (int g = 0; g < 4; ++g) {
        float bv = bias[g * 64 + ch];
        f32x4 bi = (f32x4){bv, bv, bv, bv};
        #pragma unroll
        for (int mt = 0; mt < 4; ++mt) acc[mt][g] = bi;
    }

    // ---- prologue: fill both register slots ----
    bf16x8 b0[4], b1[4];
    loadB(0, b0);
    if constexpr (NS > 1) loadB(1, b1);

    // ---- K-loop: fully unrolled; slot parity is compile-time so b0/b1
    // stay in registers. Compiler inserts counted vmcnt before first use
    // of each slot (data dependency), so loads for s+1, s+2 remain in
    // flight while step s computes. No LDS writes in the loop -> no
    // barriers needed.
    #pragma unroll
    for (int s = 0; s < NS; ++s) {
        bf16x8* bcur = (s & 1) ? b1 : b0;

        bf16x8 a[4];
        if (s < 9) {
            int taplin = (s / 3) * 10 + (s % 3);
            #pragma unroll
            for (int mt = 0; mt < 4; ++mt)
                a[mt] = *(const bf16x8*)(xs_s + xb[mt] + taplin * 40);
        } else {
            int ss = s - 9, tap = ss >> 1, half = ss & 1;
            int taplin = (tap / 3) * 10 + (tap % 3);
            #pragma unroll
            for (int mt = 0; mt < 4; ++mt)
                a[mt] = *(const bf16x8*)(hs_s + hb_[mt] + taplin * 72 + half * 32);
        }

        #pragma unroll
        for (int g = 0; g < 4; ++g)
            #pragma unroll
            for (int mt = 0; mt < 4; ++mt)
                acc[mt][g] = __builtin_amdgcn_mfma_f32_16x16x32_bf16(a[mt], bcur[g], acc[mt][g], 0, 0, 0);

        // refill the slot we just consumed (2 iterations of slack before
        // its next use)
        if (s + 2 < NS) loadB(s + 2, bcur);
    }

    // ---- epilogue: gates + state update ----
    // C/D layout: col = lane&15 (channel), row = quad*4 + r (pixel)
    #pragma unroll
    for (int mt = 0; mt < 4; ++mt) {
        #pragma unroll
        for (int r = 0; r < 4; ++r) {
            int p = mt * 16 + quad * 4 + r;
            int py = p >> 3, px = p & 7;
            size_t gidx = (((size_t)b * 64 + (gy0 + py)) * 64 + (gx0 + px)) * 64 + ch;
            float zi = acc[mt][0][r];
            float zf = acc[mt][1][r];
            float zc = acc[mt][2][r];
            float zo = acc[mt][3][r];
            float c_prev = HP ? c_st[gidx] : 0.0f;
            float cn = hsig(zf) * c_prev + hsig(zi) * fmaxf(zc, 0.0f);
            float hn = hsig(zo) * fmaxf(cn, 0.0f);
            if (is_last) {
                c_st[gidx] = hn;            // d_out gets final h (fp32)
            } else {
                c_st[gidx] = cn;
                h_out[gidx] = f2bf(hn);
            }
        }
    }
}

extern "C" void kernel_launch(void* const* d_in, const int* in_sizes, int n_in,
                              void* d_out, int out_size, void* d_ws, size_t ws_size,
                              hipStream_t stream) {
    const float* x  = (const float*)d_in[0];
    const float* Wg = (const float*)d_in[1];
    const float* Ug = (const float*)d_in[2];
    const float* bs = (const float*)d_in[3];

    // ws layout: [packed weights 442368 B][h0 bf16 4 MB][h1 bf16 4 MB]
    unsigned short* wpk = (unsigned short*)d_ws;
    unsigned short* h0  = (unsigned short*)((char*)d_ws + 27 * 16 * 64 * 8 * 2);
    unsigned short* h1  = h0 + (size_t)8 * 64 * 64 * 64;
    float* cS = (float*)d_out;

    prepack_w<<<108, 256, 0, stream>>>(Wg, Ug, wpk);

    dim3 grid(8, 8, 8);
    dim3 block(256);
    for (int t = 0; t < TSTEPS; ++t) {
        const unsigned short* hin = (t == 0) ? h0 : ((t & 1) ? h0 : h1);
        unsigned short* hout = (t & 1) ? h1 : h0;
        if (t == 0) {
            convlstm_step<9><<<grid, block, 0, stream>>>(x, wpk, bs, hin, cS, hout, t, 0);
        } else {
            convlstm_step<27><<<grid, block, 0, stream>>>(x, wpk, bs, hin, cS, hout,
                                                          t, (t == TSTEPS - 1) ? 1 : 0);
        }
    }
}

// Round 2
// 435.833 us; speedup vs baseline: 1.1291x; 1.1291x over previous
//
#include <hip/hip_runtime.h>

// ConvLSTM2D via MFMA implicit-GEMM. B=8,T=16,H=W=64,Cin=32,F=64,3x3 SAME.
// Round 9: 128-px blocks (16x8 tile, 512 thr, 8 waves) with a SHARED B-ring.
// R7 (64-px blocks, wave-private B) measured ~= SUM of its pipes
// (MFMA 621 + LDS 1130 + L2 585 cyc/CU-iter): wave-private B makes LDS-DMA
// and L2 weight traffic scale with wave count. Here waves split 2(px-half)
// x 4(n-group); the 16 KB/k-step weight slot is DMA'd ONCE per block
// (2 nt per wave) -> LDS 941, L2 292 cyc/CU-iter. Ring depth P=4 with one
// raw s_barrier per k-iter (8-phase-GEMM idiom): slot overwritten by
// issueDMA(s+3) is slot s-1, whose reads are complete once all waves pass
// barrier(s) (lgkm waits precede MFMA(s-1) which precedes barrier(s)).
// sched_barrier(0) after each s_barrier pins ds_reads inside their segment
// (raw s_barrier is NOT an LLVM memory fence). Counted vmcnt: each wave
// certifies only ITS OWN 2 slot-s loads before the barrier publishes all.
//
// R8 lesson (global->VGPR streaming, +11%): compiler clusters its vmcnt
// right before use; at 2 waves/SIMD nothing hides L2 latency. Ring + hand
// vmcnt is the schedulable path.

#define TSTEPS 16

typedef short bf16x8 __attribute__((ext_vector_type(8)));
typedef float f32x4 __attribute__((ext_vector_type(4)));
typedef unsigned int __attribute__((address_space(1))) gu32;
typedef unsigned int __attribute__((address_space(3))) lu32;

__device__ __forceinline__ float hsig(float x) {
    return fminf(fmaxf((x + 3.0f) * (1.0f / 6.0f), 0.0f), 1.0f);
}

__device__ __forceinline__ unsigned short f2bf(float f) {
    union { float f; unsigned int u; } v; v.f = f;
    unsigned int r = v.u + 0x7fffu + ((v.u >> 16) & 1u);  // RNE
    return (unsigned short)(r >> 16);
}

// ---- weight prepack: Wg(3,3,32,256), Ug(3,3,64,256) fp32 -> bf16 B-frags ----
__global__ __launch_bounds__(256)
void prepack_w(const float* __restrict__ Wg, const float* __restrict__ Ug,
               unsigned short* __restrict__ out)
{
    int idx = blockIdx.x * 256 + threadIdx.x;   // 27*16*64 = 27648
    if (idx >= 27648) return;
    int lane = idx & 63;
    int nt   = (idx >> 6) & 15;
    int s    = idx >> 10;
    int col = lane & 15, quad = lane >> 4;
    int n = nt * 16 + col;
    int k0 = quad * 8;
    const float* src;
    if (s < 9) {
        src = Wg + ((size_t)s * 32 + k0) * 256 + n;
    } else {
        int ss = s - 9; int tap = ss >> 1; int half = ss & 1;
        src = Ug + ((size_t)tap * 64 + half * 32 + k0) * 256 + n;
    }
    unsigned short tmp[8];
    #pragma unroll
    for (int j = 0; j < 8; ++j) tmp[j] = f2bf(src[(size_t)j * 256]);
    *(uint4*)(out + (size_t)idx * 8) = *(uint4*)tmp;
}

// ---- one ConvLSTM step (NS = 9 for t==0, 27 otherwise) ----
template<int NS>
__global__ __launch_bounds__(512)
__attribute__((amdgpu_waves_per_eu(2, 2)))
void convlstm_step(const float* __restrict__ x,       // (B,T,64,64,32) fp32
                   const unsigned short* __restrict__ wpk,
                   const float* __restrict__ bias,    // (256)
                   const unsigned short* __restrict__ h_in, // bf16 (B,64,64,64)
                   float* __restrict__ c_st,          // fp32 (B,64,64,64) = d_out
                   unsigned short* __restrict__ h_out,// bf16 ping
                   int t, int is_last)
{
    constexpr bool HP = (NS == 27);
    constexpr int  P  = 4;   // B ring depth (slots)

    // tile: 16 rows (y) x 8 cols (x) = 128 px; halo 18x10 = 180 px
    __shared__ __align__(16) unsigned short xs_s[180 * 40];           // 14.4 KB
    __shared__ __align__(16) unsigned short hs_s[HP ? 180 * 72 : 8];  // 25.9 KB
    __shared__ __align__(16) unsigned short bring[P * 16 * 512];      // 64.0 KB

    const int tid = threadIdx.x;
    const int gx0 = blockIdx.x * 8;
    const int gy0 = blockIdx.y * 16;
    const int b   = blockIdx.z;

    const int lane  = tid & 63;
    const int w     = tid >> 6;        // wave 0..7
    const int pxgrp = w >> 2;          // 0: rows 0-7, 1: rows 8-15
    const int ngrp  = w & 3;           // n-group: nt in {ngrp, ngrp+4, ngrp+8, ngrp+12}
    const int quad  = lane >> 4;
    const int m     = lane & 15;
    const int col   = m;
    const int ch    = ngrp * 16 + col; // output channel 0..63

    // ---- B DMA: wave w stages nt {w, w+8} for k-step s into slot s%P.
    // Wave-uniform LDS base + lane*16 (the global_load_lds shape).
    auto issueDMA = [&](int s) {
        int slot = s & (P - 1);
        #pragma unroll
        for (int g = 0; g < 2; ++g) {
            int nt = w + 8 * g;
            const unsigned short* gp = wpk + ((size_t)(s * 16 + nt) * 64 + lane) * 8;
            unsigned short* lp = bring + ((size_t)slot * 16 + nt) * 512;  // uniform
            __builtin_amdgcn_global_load_lds((const gu32*)gp, (lu32*)lp, 16, 0, 0);
        }
    };

    // ---- prologue: start filling the ring before staging (the staging
    // __syncthreads drains vmcnt, so slots 0-2 are resident at loop entry)
    issueDMA(0);
    issueDMA(1);
    issueDMA(2);

    // ---- stage x halo (fp32 -> bf16) ----
    {
        const float* xt = x + (((size_t)b * TSTEPS + t) * (size_t)(64 * 64 * 32));
        #pragma unroll 3
        for (int idx = tid; idx < 180 * 8; idx += 512) {
            int pix = idx >> 3, q = idx & 7;
            int iy = pix / 10, ix = pix - iy * 10;
            int gy = gy0 + iy - 1, gx = gx0 + ix - 1;
            unsigned short o[4] = {0, 0, 0, 0};
            if ((unsigned)gy < 64u && (unsigned)gx < 64u) {
                float4 v = *(const float4*)(xt + ((size_t)(gy * 64 + gx) * 32) + q * 4);
                o[0] = f2bf(v.x); o[1] = f2bf(v.y); o[2] = f2bf(v.z); o[3] = f2bf(v.w);
            }
            *(ushort4*)(xs_s + pix * 40 + q * 4) = *(ushort4*)o;
        }
    }
    // ---- stage h halo (bf16 copy) ----
    if constexpr (HP) {
        const unsigned short* hb = h_in + ((size_t)b * (64 * 64 * 64));
        #pragma unroll 3
        for (int idx = tid; idx < 180 * 8; idx += 512) {
            int pix = idx >> 3, q = idx & 7;
            int iy = pix / 10, ix = pix - iy * 10;
            int gy = gy0 + iy - 1, gx = gx0 + ix - 1;
            uint4 v = make_uint4(0u, 0u, 0u, 0u);
            if ((unsigned)gy < 64u && (unsigned)gx < 64u)
                v = *(const uint4*)(hb + ((size_t)(gy * 64 + gx) * 64) + q * 8);
            *(uint4*)(hs_s + pix * 72 + q * 8) = v;
        }
    }
    __syncthreads();   // staging visible; drains vmcnt (ring slots 0-2 land)

    int xb[4], hb_[4];
    #pragma unroll
    for (int mt = 0; mt < 4; ++mt) {
        int p = mt * 16 + m;
        int row = pxgrp * 8 + (p >> 3);
        int cc  = p & 7;
        xb[mt]  = (row * 10 + cc) * 40 + quad * 8;
        hb_[mt] = (row * 10 + cc) * 72 + quad * 8;
    }

    // acc init = bias
    f32x4 acc[4][4];   // [mt][gate]
    #pragma unroll
    for (int g = 0; g < 4; ++g) {
        float bv = bias[g * 64 + ch];
        f32x4 bi = (f32x4){bv, bv, bv, bv};
        #pragma unroll
        for (int mt = 0; mt < 4; ++mt) acc[mt][g] = bi;
    }

    // ---- K-loop: one barrier per iter, counted vmcnt, P=4 ring ----
    #pragma unroll
    for (int s = 0; s < NS; ++s) {
        // Certify MY slot-s loads (2 per slot; up to slots s+1,s+2 = 4 in
        // flight stay pending). imm: vmcnt[3:0], exp=7, lgkm=15.
        if (s + 2 < NS)      __builtin_amdgcn_s_waitcnt(0xF74);  // vmcnt(4)
        else if (s + 1 < NS) __builtin_amdgcn_s_waitcnt(0xF72);  // vmcnt(2)
        else                 __builtin_amdgcn_s_waitcnt(0xF70);  // vmcnt(0)
        __builtin_amdgcn_s_barrier();          // publish all waves' slot-s
        __builtin_amdgcn_sched_barrier(0);     // pin ds_reads below barrier

        const int slot = s & (P - 1);
        bf16x8 bfr[4];
        #pragma unroll
        for (int g = 0; g < 4; ++g)
            bfr[g] = *(const bf16x8*)(bring + ((size_t)slot * 16 + (ngrp + 4 * g)) * 512 + lane * 8);

        bf16x8 a[4];
        if (s < 9) {
            int taplin = (s / 3) * 10 + (s % 3);
            #pragma unroll
            for (int mt = 0; mt < 4; ++mt)
                a[mt] = *(const bf16x8*)(xs_s + xb[mt] + taplin * 40);
        } else {
            int ss = s - 9, tap = ss >> 1, half = ss & 1;
            int taplin = (tap / 3) * 10 + (tap % 3);
            #pragma unroll
            for (int mt = 0; mt < 4; ++mt)
                a[mt] = *(const bf16x8*)(hs_s + hb_[mt] + taplin * 72 + half * 32);
        }

        #pragma unroll
        for (int g = 0; g < 4; ++g)
            #pragma unroll
            for (int mt = 0; mt < 4; ++mt)
                acc[mt][g] = __builtin_amdgcn_mfma_f32_16x16x32_bf16(a[mt], bfr[g], acc[mt][g], 0, 0, 0);

        // refill: writes slot (s+3)%4 = (s-1)%4, safe per barrier argument
        if (s + 3 < NS) issueDMA(s + 3);
    }

    // ---- epilogue: gates + state update ----
    // C/D layout: col = lane&15 (channel), row = quad*4 + r (pixel)
    #pragma unroll
    for (int mt = 0; mt < 4; ++mt) {
        #pragma unroll
        for (int r = 0; r < 4; ++r) {
            int p = mt * 16 + quad * 4 + r;
            int py = pxgrp * 8 + (p >> 3), px = p & 7;
            size_t gidx = (((size_t)b * 64 + (gy0 + py)) * 64 + (gx0 + px)) * 64 + ch;
            float zi = acc[mt][0][r];
            float zf = acc[mt][1][r];
            float zc = acc[mt][2][r];
            float zo = acc[mt][3][r];
            float c_prev = HP ? c_st[gidx] : 0.0f;
            float cn = hsig(zf) * c_prev + hsig(zi) * fmaxf(zc, 0.0f);
            float hn = hsig(zo) * fmaxf(cn, 0.0f);
            if (is_last) {
                c_st[gidx] = hn;            // d_out gets final h (fp32)
            } else {
                c_st[gidx] = cn;
                h_out[gidx] = f2bf(hn);
            }
        }
    }
}

extern "C" void kernel_launch(void* const* d_in, const int* in_sizes, int n_in,
                              void* d_out, int out_size, void* d_ws, size_t ws_size,
                              hipStream_t stream) {
    const float* x  = (const float*)d_in[0];
    const float* Wg = (const float*)d_in[1];
    const float* Ug = (const float*)d_in[2];
    const float* bs = (const float*)d_in[3];

    // ws layout: [packed weights 442368 B][h0 bf16 4 MB][h1 bf16 4 MB]
    unsigned short* wpk = (unsigned short*)d_ws;
    unsigned short* h0  = (unsigned short*)((char*)d_ws + 27 * 16 * 64 * 8 * 2);
    unsigned short* h1  = h0 + (size_t)8 * 64 * 64 * 64;
    float* cS = (float*)d_out;

    prepack_w<<<108, 256, 0, stream>>>(Wg, Ug, wpk);

    dim3 grid(8, 4, 8);   // 8 x-tiles, 4 y-tiles (16 rows each), 8 batches
    dim3 block(512);
    for (int t = 0; t < TSTEPS; ++t) {
        const unsigned short* hin = (t == 0) ? h0 : ((t & 1) ? h0 : h1);
        unsigned short* hout = (t & 1) ? h1 : h0;
        if (t == 0) {
            convlstm_step<9><<<grid, block, 0, stream>>>(x, wpk, bs, hin, cS, hout, t, 0);
        } else {
            convlstm_step<27><<<grid, block, 0, stream>>>(x, wpk, bs, hin, cS, hout,
                                                          t, (t == TSTEPS - 1) ? 1 : 0);
        }
    }
}

// Round 3
// 428.611 us; speedup vs baseline: 1.1481x; 1.0169x over previous
//
#include <hip/hip_runtime.h>

// ConvLSTM2D via MFMA implicit-GEMM. B=8,T=16,H=W=64,Cin=32,F=64,3x3 SAME.
// Round 10: cross-barrier software pipeline. R9's one-barrier-per-k-iter
// put all 8 waves in phase lockstep ([barrier, ds_read burst, MFMA burst]
// repeated) so the CU ran at the SUM of LDS+MFMA pipe time (~2178 cyc/iter
// vs pipes 730+620). Fix: certify one extra ring slot per barrier
// (vmcnt(2): my s+1,s+2 DMAs done -> barrier publishes slots s+1 AND s+2),
// and prefetch step s+1's A/B fragments into a second register set BEFORE
// step s's MFMA cluster. ds_reads of s+1 now overlap MFMAs of s; no
// barrier sits between a ds_read and its dependent MFMA.
// Safety: DMA(s+3) overwrites slot (s-1)&3, whose prefetch reads
// lgkm-completed before MFMA(s-1) (iter s-1), which precedes the barrier
// ending iter s-1, which precedes DMA(s+3) (iter s).
// sched_barrier(0) fences: after each s_barrier (raw s_barrier is NOT an
// LLVM memory fence -- new-slot reads must not float above it), between
// prefetch reads and MFMAs (reads stay early), before vmcnt+barrier
// (nothing sinks past). setprio(1) around MFMA: the pipeline creates wave
// role-diversity, the regime where setprio is proven to pay.
//
// Structure: 128-px blocks (16x8, 512 thr, 8 waves), waves = 2(px-half) x
// 4(n-group); shared B-ring P=4, 16 KB/slot, DMA'd once per block per
// k-step. A halos in LDS bf16 (pad 40/72). h ping-pongs bf16 in ws; c fp32
// in d_out.

#define TSTEPS 16

typedef short bf16x8 __attribute__((ext_vector_type(8)));
typedef float f32x4 __attribute__((ext_vector_type(4)));
typedef unsigned int __attribute__((address_space(1))) gu32;
typedef unsigned int __attribute__((address_space(3))) lu32;

__device__ __forceinline__ float hsig(float x) {
    return fminf(fmaxf((x + 3.0f) * (1.0f / 6.0f), 0.0f), 1.0f);
}

__device__ __forceinline__ unsigned short f2bf(float f) {
    union { float f; unsigned int u; } v; v.f = f;
    unsigned int r = v.u + 0x7fffu + ((v.u >> 16) & 1u);  // RNE
    return (unsigned short)(r >> 16);
}

// ---- weight prepack: Wg(3,3,32,256), Ug(3,3,64,256) fp32 -> bf16 B-frags ----
__global__ __launch_bounds__(256)
void prepack_w(const float* __restrict__ Wg, const float* __restrict__ Ug,
               unsigned short* __restrict__ out)
{
    int idx = blockIdx.x * 256 + threadIdx.x;   // 27*16*64 = 27648
    if (idx >= 27648) return;
    int lane = idx & 63;
    int nt   = (idx >> 6) & 15;
    int s    = idx >> 10;
    int col = lane & 15, quad = lane >> 4;
    int n = nt * 16 + col;
    int k0 = quad * 8;
    const float* src;
    if (s < 9) {
        src = Wg + ((size_t)s * 32 + k0) * 256 + n;
    } else {
        int ss = s - 9; int tap = ss >> 1; int half = ss & 1;
        src = Ug + ((size_t)tap * 64 + half * 32 + k0) * 256 + n;
    }
    unsigned short tmp[8];
    #pragma unroll
    for (int j = 0; j < 8; ++j) tmp[j] = f2bf(src[(size_t)j * 256]);
    *(uint4*)(out + (size_t)idx * 8) = *(uint4*)tmp;
}

// ---- one ConvLSTM step (NS = 9 for t==0, 27 otherwise) ----
template<int NS>
__global__ __launch_bounds__(512)
__attribute__((amdgpu_waves_per_eu(2, 2)))
void convlstm_step(const float* __restrict__ x,       // (B,T,64,64,32) fp32
                   const unsigned short* __restrict__ wpk,
                   const float* __restrict__ bias,    // (256)
                   const unsigned short* __restrict__ h_in, // bf16 (B,64,64,64)
                   float* __restrict__ c_st,          // fp32 (B,64,64,64) = d_out
                   unsigned short* __restrict__ h_out,// bf16 ping
                   int t, int is_last)
{
    constexpr bool HP = (NS == 27);
    constexpr int  P  = 4;   // B ring depth (slots)

    // tile: 16 rows (y) x 8 cols (x) = 128 px; halo 18x10 = 180 px
    __shared__ __align__(16) unsigned short xs_s[180 * 40];           // 14.4 KB
    __shared__ __align__(16) unsigned short hs_s[HP ? 180 * 72 : 8];  // 25.9 KB
    __shared__ __align__(16) unsigned short bring[P * 16 * 512];      // 64.0 KB

    const int tid = threadIdx.x;
    const int gx0 = blockIdx.x * 8;
    const int gy0 = blockIdx.y * 16;
    const int b   = blockIdx.z;

    const int lane  = tid & 63;
    const int w     = tid >> 6;        // wave 0..7
    const int pxgrp = w >> 2;          // 0: rows 0-7, 1: rows 8-15
    const int ngrp  = w & 3;           // n-group: nt in {ngrp, ngrp+4, ngrp+8, ngrp+12}
    const int quad  = lane >> 4;
    const int m     = lane & 15;
    const int col   = m;
    const int ch    = ngrp * 16 + col; // output channel 0..63

    // ---- B DMA: wave w stages nt {w, w+8} for k-step s into slot s%P ----
    auto issueDMA = [&](int s) {
        int slot = s & (P - 1);
        #pragma unroll
        for (int g = 0; g < 2; ++g) {
            int nt = w + 8 * g;
            const unsigned short* gp = wpk + ((size_t)(s * 16 + nt) * 64 + lane) * 8;
            unsigned short* lp = bring + ((size_t)slot * 16 + nt) * 512;  // uniform
            __builtin_amdgcn_global_load_lds((const gu32*)gp, (lu32*)lp, 16, 0, 0);
        }
    };

    // ---- prologue: start filling the ring before staging (the staging
    // __syncthreads drains vmcnt, so slots 0-2 are resident at loop entry)
    issueDMA(0);
    issueDMA(1);
    issueDMA(2);

    // ---- stage x halo (fp32 -> bf16) ----
    {
        const float* xt = x + (((size_t)b * TSTEPS + t) * (size_t)(64 * 64 * 32));
        #pragma unroll 3
        for (int idx = tid; idx < 180 * 8; idx += 512) {
            int pix = idx >> 3, q = idx & 7;
            int iy = pix / 10, ix = pix - iy * 10;
            int gy = gy0 + iy - 1, gx = gx0 + ix - 1;
            unsigned short o[4] = {0, 0, 0, 0};
            if ((unsigned)gy < 64u && (unsigned)gx < 64u) {
                float4 v = *(const float4*)(xt + ((size_t)(gy * 64 + gx) * 32) + q * 4);
                o[0] = f2bf(v.x); o[1] = f2bf(v.y); o[2] = f2bf(v.z); o[3] = f2bf(v.w);
            }
            *(ushort4*)(xs_s + pix * 40 + q * 4) = *(ushort4*)o;
        }
    }
    // ---- stage h halo (bf16 copy) ----
    if constexpr (HP) {
        const unsigned short* hb = h_in + ((size_t)b * (64 * 64 * 64));
        #pragma unroll 3
        for (int idx = tid; idx < 180 * 8; idx += 512) {
            int pix = idx >> 3, q = idx & 7;
            int iy = pix / 10, ix = pix - iy * 10;
            int gy = gy0 + iy - 1, gx = gx0 + ix - 1;
            uint4 v = make_uint4(0u, 0u, 0u, 0u);
            if ((unsigned)gy < 64u && (unsigned)gx < 64u)
                v = *(const uint4*)(hb + ((size_t)(gy * 64 + gx) * 64) + q * 8);
            *(uint4*)(hs_s + pix * 72 + q * 8) = v;
        }
    }
    __syncthreads();   // staging + ring slots 0-2 visible (full vmcnt drain)

    int xb[4], hb_[4];
    #pragma unroll
    for (int mt = 0; mt < 4; ++mt) {
        int p = mt * 16 + m;
        int row = pxgrp * 8 + (p >> 3);
        int cc  = p & 7;
        xb[mt]  = (row * 10 + cc) * 40 + quad * 8;
        hb_[mt] = (row * 10 + cc) * 72 + quad * 8;
    }

    // acc init = bias
    f32x4 acc[4][4];   // [mt][gate]
    #pragma unroll
    for (int g = 0; g < 4; ++g) {
        float bv = bias[g * 64 + ch];
        f32x4 bi = (f32x4){bv, bv, bv, bv};
        #pragma unroll
        for (int mt = 0; mt < 4; ++mt) acc[mt][g] = bi;
    }

    // ---- fragment loads (compile-time s; fully unrolled loop) ----
    auto ldB = [&](int s, bf16x8* dst) {
        const int slot = s & (P - 1);
        #pragma unroll
        for (int g = 0; g < 4; ++g)
            dst[g] = *(const bf16x8*)(bring + ((size_t)slot * 16 + (ngrp + 4 * g)) * 512 + lane * 8);
    };
    auto ldA = [&](int s, bf16x8* dst) {
        if (s < 9) {
            int taplin = (s / 3) * 10 + (s % 3);
            #pragma unroll
            for (int mt = 0; mt < 4; ++mt)
                dst[mt] = *(const bf16x8*)(xs_s + xb[mt] + taplin * 40);
        } else {
            int ss = s - 9, tap = ss >> 1, half = ss & 1;
            int taplin = (tap / 3) * 10 + (tap % 3);
            #pragma unroll
            for (int mt = 0; mt < 4; ++mt)
                dst[mt] = *(const bf16x8*)(hs_s + hb_[mt] + taplin * 72 + half * 32);
        }
    };

    // ---- K-loop: cross-barrier pipelined ----
    bf16x8 aC[4], bC[4], aN[4], bN[4];
    ldA(0, aC); ldB(0, bC);

    #pragma unroll
    for (int s = 0; s < NS; ++s) {
        // prefetch step s+1 fragments. Slot s+1 was published by the
        // barrier ending iter s-1 (vmcnt(2) certified s+1,s+2 there); for
        // s=0 the staging __syncthreads published slots 0-2.
        if (s + 1 < NS) { ldA(s + 1, aN); ldB(s + 1, bN); }

        __builtin_amdgcn_sched_barrier(0);   // reads stay above MFMA cluster

        __builtin_amdgcn_s_setprio(1);
        #pragma unroll
        for (int g = 0; g < 4; ++g)
            #pragma unroll
            for (int mt = 0; mt < 4; ++mt)
                acc[mt][g] = __builtin_amdgcn_mfma_f32_16x16x32_bf16(aC[mt], bC[g], acc[mt][g], 0, 0, 0);
        __builtin_amdgcn_s_setprio(0);

        // refill: writes slot (s+3)&3 = (s-1)&3; its prefetch reads
        // completed before MFMA(s-1), which precedes the barrier ending
        // iter s-1, which precedes this point.
        if (s + 3 < NS) issueDMA(s + 3);

        if (s + 1 < NS) {
            __builtin_amdgcn_sched_barrier(0);  // nothing sinks past barrier
            // certify my DMAs through step s+2 (leave s+3's 2 loads pending)
            if (s + 3 < NS) __builtin_amdgcn_s_waitcnt(0xF72);  // vmcnt(2)
            else            __builtin_amdgcn_s_waitcnt(0xF70);  // vmcnt(0)
            __builtin_amdgcn_s_barrier();       // publish slots s+1, s+2
            __builtin_amdgcn_sched_barrier(0);  // next iter's reads stay below
            #pragma unroll
            for (int i = 0; i < 4; ++i) { aC[i] = aN[i]; bC[i] = bN[i]; }
        }
    }

    // ---- epilogue: gates + state update ----
    // C/D layout: col = lane&15 (channel), row = quad*4 + r (pixel)
    #pragma unroll
    for (int mt = 0; mt < 4; ++mt) {
        #pragma unroll
        for (int r = 0; r < 4; ++r) {
            int p = mt * 16 + quad * 4 + r;
            int py = pxgrp * 8 + (p >> 3), px = p & 7;
            size_t gidx = (((size_t)b * 64 + (gy0 + py)) * 64 + (gx0 + px)) * 64 + ch;
            float zi = acc[mt][0][r];
            float zf = acc[mt][1][r];
            float zc = acc[mt][2][r];
            float zo = acc[mt][3][r];
            float c_prev = HP ? c_st[gidx] : 0.0f;
            float cn = hsig(zf) * c_prev + hsig(zi) * fmaxf(zc, 0.0f);
            float hn = hsig(zo) * fmaxf(cn, 0.0f);
            if (is_last) {
                c_st[gidx] = hn;            // d_out gets final h (fp32)
            } else {
                c_st[gidx] = cn;
                h_out[gidx] = f2bf(hn);
            }
        }
    }
}

extern "C" void kernel_launch(void* const* d_in, const int* in_sizes, int n_in,
                              void* d_out, int out_size, void* d_ws, size_t ws_size,
                              hipStream_t stream) {
    const float* x  = (const float*)d_in[0];
    const float* Wg = (const float*)d_in[1];
    const float* Ug = (const float*)d_in[2];
    const float* bs = (const float*)d_in[3];

    // ws layout: [packed weights 442368 B][h0 bf16 4 MB][h1 bf16 4 MB]
    unsigned short* wpk = (unsigned short*)d_ws;
    unsigned short* h0  = (unsigned short*)((char*)d_ws + 27 * 16 * 64 * 8 * 2);
    unsigned short* h1  = h0 + (size_t)8 * 64 * 64 * 64;
    float* cS = (float*)d_out;

    prepack_w<<<108, 256, 0, stream>>>(Wg, Ug, wpk);

    dim3 grid(8, 4, 8);   // 8 x-tiles, 4 y-tiles (16 rows each), 8 batches
    dim3 block(512);
    for (int t = 0; t < TSTEPS; ++t) {
        const unsigned short* hin = (t == 0) ? h0 : ((t & 1) ? h0 : h1);
        unsigned short* hout = (t & 1) ? h1 : h0;
        if (t == 0) {
            convlstm_step<9><<<grid, block, 0, stream>>>(x, wpk, bs, hin, cS, hout, t, 0);
        } else {
            convlstm_step<27><<<grid, block, 0, stream>>>(x, wpk, bs, hin, cS, hout,
                                                          t, (t == TSTEPS - 1) ? 1 : 0);
        }
    }
}